// Round 1
// baseline (7153.333 us; speedup 1.0000x reference)
//
#include <hip/hip_runtime.h>
#include <cfloat>
#include <math.h>

#define B_ 64
#define P_ 196
#define ENC_ 2048
#define E_ 512
#define D_ 512
#define A_ 512
#define V_ 32000
#define L_ 32
#define T_ 31

// flat f32 output layout (reference return order)
#define OUT_PREDS 0L
#define OUT_CAPS  63488000L              // 64*31*32000
#define OUT_DECL  63490048L              // +64*32
#define OUT_ALPH  63490112L              // +64
#define OUT_ORDER 63878976L              // +64*31*196

static __device__ __forceinline__ float sigmoidf_(float x) { return 1.f / (1.f + __expf(-x)); }

// ---------------- sort by length, caps gather, scalar outputs ----------------
__global__ void k_order(const int* __restrict__ cap_len, const int* __restrict__ caps,
                        int* __restrict__ order_i, int* __restrict__ declen_i,
                        int* __restrict__ caps_i, float* __restrict__ out)
{
    __shared__ int len_s[B_];
    int tid = threadIdx.x;
    len_s[tid] = cap_len[tid];
    __syncthreads();
    int li = len_s[tid];
    int pos = 0;
    for (int j = 0; j < B_; ++j) {
        int lj = len_s[j];
        pos += (lj > li) || (lj == li && j < tid);   // stable descending rank
    }
    order_i[pos]  = tid;
    declen_i[pos] = li - 1;
    out[OUT_ORDER + pos] = (float)tid;
    out[OUT_DECL  + pos] = (float)(li - 1);
    for (int l = 0; l < L_; ++l) {
        int tok = caps[tid * L_ + l];
        caps_i[pos * L_ + l] = tok;
        out[OUT_CAPS + pos * L_ + l] = (float)tok;
    }
}

// ---------------- mean over pixels ----------------
__global__ __launch_bounds__(256) void k_mean(const float* __restrict__ enc,
                                              const int* __restrict__ order_i,
                                              float* __restrict__ mean_enc)
{
    int b = blockIdx.x, tid = threadIdx.x;
    int ob = order_i[b];
    const float* eb = enc + (long)ob * P_ * ENC_;
    for (int c0 = 0; c0 < ENC_; c0 += 256) {
        int col = c0 + tid;
        float s = 0.f;
        for (int p = 0; p < P_; ++p) s += eb[(long)p * ENC_ + col];
        mean_enc[(long)b * ENC_ + col] = s * (1.f / (float)P_);
    }
}

// ---------------- generic f32 GEMM: C[M][N] = A[M][K] * B[N][K]^T ----------------
// BM=BN=64, BK=32, 256 threads, 4x4 microtile. Optional split-K (EPI_RAW partials),
// optional A-row indirection (rmap: batch gather), epilogues.
enum { EPI_RAW = 0, EPI_BIAS = 1, EPI_PREDS = 2 };

template<int EPI>
__global__ void __launch_bounds__(256)
k_gemm(const float* __restrict__ Ap, const float* __restrict__ Bp,
       const float* __restrict__ bias, float* __restrict__ Cp,
       int M, int N, int K, int kspl,
       const int* __restrict__ rmap, int rchunk,
       int t, const int* __restrict__ declen_i)
{
    __shared__ __align__(16) float As[32][68];
    __shared__ __align__(16) float Bs[32][68];
    const int tid = threadIdx.x;
    const int ty = tid >> 4, tx = tid & 15;
    const int mt = blockIdx.x, nt = blockIdx.y, sz = blockIdx.z;
    const int kspan = K / kspl;
    const int k0 = sz * kspan, k1 = k0 + kspan;
    const int lrow = tid & 63, lkq = tid >> 6;

    int arow = mt * 64 + lrow;
    long aoff;
    if (rmap) { int bi = arow / rchunk; int rr = arow - bi * rchunk;
                aoff = ((long)rmap[bi] * rchunk + rr) * (long)K; }
    else       aoff = (long)arow * K;
    const float* Arow = Ap + aoff;
    const float* Brow = Bp + (long)(nt * 64 + lrow) * K;

    float acc[4][4] = {};

    for (int kk = k0; kk < k1; kk += 32) {
        const float4 a0 = *(const float4*)(Arow + kk + lkq * 8);
        const float4 a1 = *(const float4*)(Arow + kk + lkq * 8 + 4);
        const float4 b0 = *(const float4*)(Brow + kk + lkq * 8);
        const float4 b1 = *(const float4*)(Brow + kk + lkq * 8 + 4);
        __syncthreads();
        As[lkq*8+0][lrow]=a0.x; As[lkq*8+1][lrow]=a0.y; As[lkq*8+2][lrow]=a0.z; As[lkq*8+3][lrow]=a0.w;
        As[lkq*8+4][lrow]=a1.x; As[lkq*8+5][lrow]=a1.y; As[lkq*8+6][lrow]=a1.z; As[lkq*8+7][lrow]=a1.w;
        Bs[lkq*8+0][lrow]=b0.x; Bs[lkq*8+1][lrow]=b0.y; Bs[lkq*8+2][lrow]=b0.z; Bs[lkq*8+3][lrow]=b0.w;
        Bs[lkq*8+4][lrow]=b1.x; Bs[lkq*8+5][lrow]=b1.y; Bs[lkq*8+6][lrow]=b1.z; Bs[lkq*8+7][lrow]=b1.w;
        __syncthreads();
#pragma unroll
        for (int k = 0; k < 32; ++k) {
            const float4 av = *(const float4*)&As[k][ty * 4];
            const float4 bv = *(const float4*)&Bs[k][tx * 4];
            acc[0][0] += av.x*bv.x; acc[0][1] += av.x*bv.y; acc[0][2] += av.x*bv.z; acc[0][3] += av.x*bv.w;
            acc[1][0] += av.y*bv.x; acc[1][1] += av.y*bv.y; acc[1][2] += av.y*bv.z; acc[1][3] += av.y*bv.w;
            acc[2][0] += av.z*bv.x; acc[2][1] += av.z*bv.y; acc[2][2] += av.z*bv.z; acc[2][3] += av.z*bv.w;
            acc[3][0] += av.w*bv.x; acc[3][1] += av.w*bv.y; acc[3][2] += av.w*bv.z; acc[3][3] += av.w*bv.w;
        }
    }

    const int mbase = mt * 64 + ty * 4, nbase = nt * 64 + tx * 4;
    if (EPI == EPI_RAW) {
        float* C = Cp + (long)sz * M * N;
#pragma unroll
        for (int i = 0; i < 4; ++i)
#pragma unroll
            for (int j = 0; j < 4; ++j)
                C[(long)(mbase + i) * N + nbase + j] = acc[i][j];
    } else if (EPI == EPI_BIAS) {
#pragma unroll
        for (int i = 0; i < 4; ++i)
#pragma unroll
            for (int j = 0; j < 4; ++j)
                Cp[(long)(mbase + i) * N + nbase + j] = acc[i][j] + bias[nbase + j];
    } else { // EPI_PREDS: masked scatter into out predictions
#pragma unroll
        for (int i = 0; i < 4; ++i) {
            int b = mbase + i;
            bool msk = t < declen_i[b];
            long base = OUT_PREDS + ((long)b * T_ + t) * V_;
#pragma unroll
            for (int j = 0; j < 4; ++j)
                Cp[base + nbase + j] = msk ? (acc[i][j] + bias[nbase + j]) : 0.f;
        }
    }
}

// ---------------- LN stats helper (blockDim=512) ----------------
static __device__ __forceinline__ void ln_stats(float x, float* r1, float* r2,
                                                float& m, float& var)
{
    int tid = threadIdx.x;
    r1[tid] = x; r2[tid] = x * x;
    __syncthreads();
    for (int s = 256; s > 0; s >>= 1) {
        if (tid < s) { r1[tid] += r1[tid + s]; r2[tid] += r2[tid + s]; }
        __syncthreads();
    }
    m = r1[0] * (1.f / 512.f);
    var = r2[0] * (1.f / 512.f) - m * m;
    __syncthreads();
}

// ---------------- init h,c = LN(mean_enc @ W^T + b) ----------------
__global__ __launch_bounds__(512)
void k_initln(const float* __restrict__ pih, const float* __restrict__ pic,
              const float* __restrict__ b_h, const float* __restrict__ b_c,
              const float* __restrict__ g_h, const float* __restrict__ be_h,
              const float* __restrict__ g_c, const float* __restrict__ be_c,
              float* __restrict__ h, float* __restrict__ c)
{
    int b = blockIdx.x, d = threadIdx.x;
    float yh = b_h[d], yc = b_c[d];
    for (int s = 0; s < 4; ++s) {
        yh += pih[((long)s * B_ + b) * D_ + d];
        yc += pic[((long)s * B_ + b) * D_ + d];
    }
    __shared__ float r1[512], r2[512];
    float m, v;
    ln_stats(yh, r1, r2, m, v);
    h[(long)b * D_ + d] = (yh - m) * rsqrtf(v + 1e-5f) * g_h[d] + be_h[d];
    ln_stats(yc, r1, r2, m, v);
    c[(long)b * D_ + d] = (yc - m) * rsqrtf(v + 1e-5f) * g_c[d] + be_c[d];
}

// ---------------- fused attention: e, softmax, alpha out, awe*gate, assemble x ----------------
__global__ __launch_bounds__(256)
void k_attn(const float* __restrict__ dg, const float* __restrict__ gg,
            const float* __restrict__ b_dec, const float* __restrict__ b_beta,
            const float* __restrict__ Wfull, const float* __restrict__ bfull,
            const float* __restrict__ att1, const float* __restrict__ enc,
            const int* __restrict__ order_i, const int* __restrict__ caps_i,
            const int* __restrict__ declen_i, const float* __restrict__ emb,
            float* __restrict__ xbuf, float* __restrict__ out, int t)
{
    int b = blockIdx.x, tid = threadIdx.x;
    __shared__ float att2s[512];
    __shared__ float wf[512];
    __shared__ float alp[P_];
    __shared__ float red[256];
    for (int i = tid; i < 512; i += 256) {
        att2s[i] = dg[(long)b * 512 + i] + dg[(long)B_ * 512 + (long)b * 512 + i] + b_dec[i];
        wf[i] = Wfull[i];
    }
    __syncthreads();
    float ev = -FLT_MAX;
    if (tid < P_) {
        const float* ar = att1 + ((long)b * P_ + tid) * 512;
        float acc = 0.f;
        for (int a = 0; a < 512; a += 4) {
            float4 v = *(const float4*)(ar + a);
            acc += fmaxf(v.x + att2s[a + 0], 0.f) * wf[a + 0];
            acc += fmaxf(v.y + att2s[a + 1], 0.f) * wf[a + 1];
            acc += fmaxf(v.z + att2s[a + 2], 0.f) * wf[a + 2];
            acc += fmaxf(v.w + att2s[a + 3], 0.f) * wf[a + 3];
        }
        ev = acc + bfull[0];
    }
    red[tid] = ev;
    __syncthreads();
    for (int s = 128; s > 0; s >>= 1) { if (tid < s) red[tid] = fmaxf(red[tid], red[tid + s]); __syncthreads(); }
    float mx = red[0];
    __syncthreads();
    float ex = (tid < P_) ? __expf(ev - mx) : 0.f;
    red[tid] = ex;
    __syncthreads();
    for (int s = 128; s > 0; s >>= 1) { if (tid < s) red[tid] += red[tid + s]; __syncthreads(); }
    float inv = 1.f / red[0];
    if (tid < P_) alp[tid] = ex * inv;
    __syncthreads();
    bool msk = t < declen_i[b];
    if (tid < P_) out[OUT_ALPH + ((long)b * T_ + t) * P_ + tid] = msk ? alp[tid] : 0.f;
    // awe = alpha^T * enc, gated; write into x[:, 512:2560]
    int ob = order_i[b];
    const float* eb = enc + (long)ob * P_ * ENC_;
    for (int c0 = 0; c0 < ENC_; c0 += 256) {
        int col = c0 + tid;
        float acc = 0.f;
        for (int p = 0; p < P_; ++p) acc += alp[p] * eb[(long)p * ENC_ + col];
        float gsum = gg[(long)b * 2048 + col] + gg[(long)B_ * 2048 + (long)b * 2048 + col] + b_beta[col];
        xbuf[(long)b * 2560 + 512 + col] = acc * sigmoidf_(gsum);
    }
    // x[:, 0:512] = embedding of token t
    int tok = caps_i[b * L_ + t];
    for (int i = tid; i < 512; i += 256)
        xbuf[(long)b * 2560 + i] = emb[(long)tok * 512 + i];
}

// ---------------- LSTM cell + 2x LayerNorm + masked state update ----------------
__global__ __launch_bounds__(512)
void k_lstm(const float* __restrict__ gp, const float* __restrict__ b_ih, const float* __restrict__ b_hh,
            const float* __restrict__ g_h, const float* __restrict__ be_h,
            const float* __restrict__ g_c, const float* __restrict__ be_c,
            float* __restrict__ h, float* __restrict__ c,
            const int* __restrict__ declen_i, int t)
{
    int b = blockIdx.x, d = threadIdx.x;
    float iv = b_ih[d]        + b_hh[d];
    float fv = b_ih[512 + d]  + b_hh[512 + d];
    float gv = b_ih[1024 + d] + b_hh[1024 + d];
    float ov = b_ih[1536 + d] + b_hh[1536 + d];
    for (int s = 0; s < 5; ++s) {
        const float* gs = gp + ((long)s * B_ + b) * 2048;
        iv += gs[d]; fv += gs[512 + d]; gv += gs[1024 + d]; ov += gs[1536 + d];
    }
    float cn = sigmoidf_(fv) * c[(long)b * 512 + d] + sigmoidf_(iv) * tanhf(gv);
    float hn = sigmoidf_(ov) * tanhf(cn);
    __shared__ float r1[512], r2[512];
    float m, v;
    ln_stats(hn, r1, r2, m, v);
    float hln = (hn - m) * rsqrtf(v + 1e-5f) * g_h[d] + be_h[d];
    ln_stats(cn, r1, r2, m, v);
    float cln = (cn - m) * rsqrtf(v + 1e-5f) * g_c[d] + be_c[d];
    if (t < declen_i[b]) {
        h[(long)b * 512 + d] = hln;
        c[(long)b * 512 + d] = cln;
    }
}

extern "C" void kernel_launch(void* const* d_in, const int* in_sizes, int n_in,
                              void* d_out, int out_size, void* d_ws, size_t ws_size,
                              hipStream_t stream)
{
    const float* enc       = (const float*)d_in[0];
    const int*   caps      = (const int*)  d_in[1];
    const int*   caplen    = (const int*)  d_in[2];
    const float* emb       = (const float*)d_in[3];
    const float* W_enc_att = (const float*)d_in[4];
    const float* b_enc_att = (const float*)d_in[5];
    const float* W_dec_att = (const float*)d_in[6];
    const float* b_dec_att = (const float*)d_in[7];
    const float* W_full    = (const float*)d_in[8];
    const float* b_full    = (const float*)d_in[9];
    const float* W_ih      = (const float*)d_in[10];
    const float* b_ih      = (const float*)d_in[11];
    const float* W_hh      = (const float*)d_in[12];
    const float* b_hh      = (const float*)d_in[13];
    const float* g_h       = (const float*)d_in[14];
    const float* be_h      = (const float*)d_in[15];
    const float* g_c       = (const float*)d_in[16];
    const float* be_c      = (const float*)d_in[17];
    const float* W_init_h  = (const float*)d_in[18];
    const float* b_init_h  = (const float*)d_in[19];
    const float* W_init_c  = (const float*)d_in[20];
    const float* b_init_c  = (const float*)d_in[21];
    const float* W_beta    = (const float*)d_in[22];
    const float* b_beta    = (const float*)d_in[23];
    const float* W_fc      = (const float*)d_in[24];
    const float* b_fc      = (const float*)d_in[25];
    float* out = (float*)d_out;

    char* w = (char*)d_ws;
    auto alloc = [&](size_t bytes) { char* p = w; w += (bytes + 255) & ~(size_t)255; return p; };
    int*   order_i  = (int*)  alloc(B_ * 4);
    int*   declen_i = (int*)  alloc(B_ * 4);
    int*   caps_i   = (int*)  alloc(B_ * L_ * 4);
    float* mean_enc = (float*)alloc((size_t)B_ * ENC_ * 4);
    float* hbuf     = (float*)alloc((size_t)B_ * D_ * 4);
    float* cbuf     = (float*)alloc((size_t)B_ * D_ * 4);
    float* att1     = (float*)alloc((size_t)B_ * P_ * A_ * 4);
    float* dg       = (float*)alloc((size_t)2 * B_ * 512 * 4);
    float* gg       = (float*)alloc((size_t)2 * B_ * 2048 * 4);
    float* gp       = (float*)alloc((size_t)5 * B_ * 2048 * 4);
    float* pih      = (float*)alloc((size_t)4 * B_ * 512 * 4);
    float* pic      = (float*)alloc((size_t)4 * B_ * 512 * 4);
    float* xbuf     = (float*)alloc((size_t)B_ * 2560 * 4);

    k_order<<<1, B_, 0, stream>>>(caplen, caps, order_i, declen_i, caps_i, out);
    k_mean<<<B_, 256, 0, stream>>>(enc, order_i, mean_enc);

    // init h,c: split-K GEMMs (M=64,N=512,K=2048,S=4) then LN
    dim3 g1(1, 8, 4);
    k_gemm<EPI_RAW><<<g1, 256, 0, stream>>>(mean_enc, W_init_h, nullptr, pih, 64, 512, 2048, 4, nullptr, 0, 0, nullptr);
    k_gemm<EPI_RAW><<<g1, 256, 0, stream>>>(mean_enc, W_init_c, nullptr, pic, 64, 512, 2048, 4, nullptr, 0, 0, nullptr);
    k_initln<<<B_, 512, 0, stream>>>(pih, pic, b_init_h, b_init_c, g_h, be_h, g_c, be_c, hbuf, cbuf);

    // att1 = enc_sorted @ W_enc_att^T + b  (M=12544,N=512,K=2048), A-row gather by order
    dim3 ga(196, 8, 1);
    k_gemm<EPI_BIAS><<<ga, 256, 0, stream>>>(enc, W_enc_att, b_enc_att, att1, 12544, 512, 2048, 1, order_i, P_, 0, nullptr);

    for (int t = 0; t < T_; ++t) {
        dim3 gd(1, 8, 2);   // att2 partials: M=64,N=512,K=512,S=2
        k_gemm<EPI_RAW><<<gd, 256, 0, stream>>>(hbuf, W_dec_att, nullptr, dg, 64, 512, 512, 2, nullptr, 0, 0, nullptr);
        dim3 gb(1, 32, 2);  // gate partials: M=64,N=2048,K=512,S=2
        k_gemm<EPI_RAW><<<gb, 256, 0, stream>>>(hbuf, W_beta, nullptr, gg, 64, 2048, 512, 2, nullptr, 0, 0, nullptr);
        k_attn<<<B_, 256, 0, stream>>>(dg, gg, b_dec_att, b_beta, W_full, b_full, att1, enc,
                                       order_i, caps_i, declen_i, emb, xbuf, out, t);
        dim3 gi(1, 32, 4);  // x @ W_ih^T partials: M=64,N=2048,K=2560,S=4 -> slots 0..3
        k_gemm<EPI_RAW><<<gi, 256, 0, stream>>>(xbuf, W_ih, nullptr, gp, 64, 2048, 2560, 4, nullptr, 0, 0, nullptr);
        dim3 gh(1, 32, 1);  // h @ W_hh^T: M=64,N=2048,K=512 -> slot 4
        k_gemm<EPI_RAW><<<gh, 256, 0, stream>>>(hbuf, W_hh, nullptr, gp + (size_t)4 * B_ * 2048, 64, 2048, 512, 1, nullptr, 0, 0, nullptr);
        k_lstm<<<B_, 512, 0, stream>>>(gp, b_ih, b_hh, g_h, be_h, g_c, be_c, hbuf, cbuf, declen_i, t);
        dim3 gf(1, 500, 1); // preds: M=64,N=32000,K=512, masked write to out
        k_gemm<EPI_PREDS><<<gf, 256, 0, stream>>>(hbuf, W_fc, b_fc, out, 64, 32000, 512, 1, nullptr, 0, t, declen_i);
    }
}

// Round 2
// 3020.131 us; speedup vs baseline: 2.3686x; 2.3686x over previous
//
#include <hip/hip_runtime.h>
#include <cfloat>
#include <math.h>

#define B_ 64
#define P_ 196
#define ENC_ 2048
#define D_ 512
#define V_ 32000
#define L_ 32
#define T_ 31

// flat f32 output layout (reference return order)
#define OUT_PREDS 0L
#define OUT_CAPS  63488000L              // 64*31*32000
#define OUT_DECL  63490048L              // +64*32
#define OUT_ALPH  63490112L              // +64
#define OUT_ORDER 63878976L              // +64*31*196

typedef __bf16 bf16;
typedef __bf16 bf16x8 __attribute__((ext_vector_type(8)));
typedef __bf16 bf16x4 __attribute__((ext_vector_type(4)));
typedef float  f32x4  __attribute__((ext_vector_type(4)));

static __device__ __forceinline__ float sigmoidf_(float x) { return 1.f / (1.f + __expf(-x)); }

// ---------------- sort by length, caps gather, scalar outputs ----------------
__global__ void k_order(const int* __restrict__ cap_len, const int* __restrict__ caps,
                        int* __restrict__ order_i, int* __restrict__ declen_i,
                        int* __restrict__ caps_i, float* __restrict__ out)
{
    __shared__ int len_s[B_];
    int tid = threadIdx.x;
    len_s[tid] = cap_len[tid];
    __syncthreads();
    int li = len_s[tid];
    int pos = 0;
    for (int j = 0; j < B_; ++j) {
        int lj = len_s[j];
        pos += (lj > li) || (lj == li && j < tid);   // stable descending rank
    }
    order_i[pos]  = tid;
    declen_i[pos] = li - 1;
    out[OUT_ORDER + pos] = (float)tid;
    out[OUT_DECL  + pos] = (float)(li - 1);
    for (int l = 0; l < L_; ++l) {
        int tok = caps[tid * L_ + l];
        caps_i[pos * L_ + l] = tok;
        out[OUT_CAPS + pos * L_ + l] = (float)tok;
    }
}

// ---------------- f32 -> bf16 convert (grid-stride-free, 8/thread) ----------------
__global__ __launch_bounds__(256) void k_cvt(const float* __restrict__ in, bf16* __restrict__ ob, long n)
{
    long i = ((long)blockIdx.x * 256 + threadIdx.x) * 8;
    if (i >= n) return;
    float4 a = *(const float4*)(in + i);
    float4 b = *(const float4*)(in + i + 4);
    bf16x8 v;
    v[0]=(bf16)a.x; v[1]=(bf16)a.y; v[2]=(bf16)a.z; v[3]=(bf16)a.w;
    v[4]=(bf16)b.x; v[5]=(bf16)b.y; v[6]=(bf16)b.z; v[7]=(bf16)b.w;
    *(bf16x8*)(ob + i) = v;
}

// ---------------- enc gather-by-order + convert to bf16 ----------------
__global__ __launch_bounds__(256) void k_cvt_enc(const float* __restrict__ enc,
                                                 const int* __restrict__ order_i,
                                                 bf16* __restrict__ enc_s)
{
    long i = ((long)blockIdx.x * 256 + threadIdx.x) * 8;
    int b = (int)(i / ((long)P_ * ENC_));
    long rem = i - (long)b * P_ * ENC_;
    const float* src = enc + (long)order_i[b] * P_ * ENC_ + rem;
    float4 a = *(const float4*)(src);
    float4 c = *(const float4*)(src + 4);
    bf16x8 v;
    v[0]=(bf16)a.x; v[1]=(bf16)a.y; v[2]=(bf16)a.z; v[3]=(bf16)a.w;
    v[4]=(bf16)c.x; v[5]=(bf16)c.y; v[6]=(bf16)c.z; v[7]=(bf16)c.w;
    *(bf16x8*)(enc_s + i) = v;
}

// ---------------- mean over pixels (bf16 in/out) ----------------
__global__ __launch_bounds__(256) void k_meanb(const bf16* __restrict__ enc_s, bf16* __restrict__ mean_b)
{
    int b = blockIdx.x, col = blockIdx.y * 256 + threadIdx.x;
    float s = 0.f;
    const bf16* eb = enc_s + (long)b * P_ * ENC_ + col;
    for (int p = 0; p < P_; ++p) s += (float)eb[(long)p * ENC_];
    mean_b[(long)b * ENC_ + col] = (bf16)(s * (1.f / (float)P_));
}

// ---------------- MFMA GEMM: C[M][N] = A[M][K](bf16) * B[N][K]^T(bf16) ------
// 256 thr = 4 waves; tile BM=64 x BN=128; wave w covers cols [w*32, w*32+32).
// No LDS: fragments loaded straight from global (L1/L2-served).
// FUSE: 0=single B, 1=N-split (B2 rows from n>=Nsp), 2=K-split (B2 cols from k>=Ksp)
// EPI:  0=RAW f32 partial slot z (M=64), 1=bf16 +bias (att1), 2=masked preds +bias
template<int FUSE, int EPI>
__global__ void __launch_bounds__(256)
k_mgemm(const bf16* __restrict__ A, long lda,
        const bf16* __restrict__ B1, const bf16* __restrict__ B2,
        const float* __restrict__ bias,
        float* __restrict__ Cf, bf16* __restrict__ Cb,
        int N, int K, int kspl, int Nsp, int Ksp,
        int t, const int* __restrict__ declen_i)
{
    const int tid = threadIdx.x;
    const int lane = tid & 63, w = tid >> 6;
    const int mt = blockIdx.x, nt = blockIdx.y, z = blockIdx.z;
    const int krange = K / kspl;
    const int k0 = z * krange, k1 = k0 + krange;
    const int r16 = lane & 15, kq = lane >> 4;
    const int koff = kq * 8;

    const bf16* Ap = A + (long)(mt * 64 + r16) * lda + koff;
    const int ncol0 = nt * 128 + w * 32;

    const bf16* Bp[2];
    const bf16* B2p[2];
#pragma unroll
    for (int ni = 0; ni < 2; ++ni) {
        int n = ncol0 + ni * 16 + r16;
        if (FUSE == 1)
            Bp[ni] = (n < Nsp) ? B1 + (long)n * K + koff
                               : B2 + (long)(n - Nsp) * K + koff;
        else if (FUSE == 2) {
            Bp[ni]  = B1 + (long)n * Ksp + koff;
            B2p[ni] = B2 + (long)n * (K - Ksp) + koff - Ksp;  // +kk yields col kk-Ksp
        } else
            Bp[ni] = B1 + (long)n * K + koff;
    }

    f32x4 acc[4][2] = {};
    for (int kk = k0; kk < k1; kk += 32) {
        bf16x8 af[4], bfr[2];
#pragma unroll
        for (int mi = 0; mi < 4; ++mi)
            af[mi] = *(const bf16x8*)(Ap + (long)mi * 16 * lda + kk);
#pragma unroll
        for (int ni = 0; ni < 2; ++ni) {
            if (FUSE == 2 && kk >= Ksp) bfr[ni] = *(const bf16x8*)(B2p[ni] + kk);
            else                        bfr[ni] = *(const bf16x8*)(Bp[ni] + kk);
        }
#pragma unroll
        for (int mi = 0; mi < 4; ++mi)
#pragma unroll
            for (int ni = 0; ni < 2; ++ni)
                acc[mi][ni] = __builtin_amdgcn_mfma_f32_16x16x32_bf16(af[mi], bfr[ni], acc[mi][ni], 0, 0, 0);
    }

    // C/D layout (m89-verified): col = lane&15, row = (lane>>4)*4 + r
#pragma unroll
    for (int mi = 0; mi < 4; ++mi) {
#pragma unroll
        for (int ni = 0; ni < 2; ++ni) {
            int col = ncol0 + ni * 16 + r16;
#pragma unroll
            for (int r = 0; r < 4; ++r) {
                int row = mt * 64 + mi * 16 + kq * 4 + r;
                float v = acc[mi][ni][r];
                if (EPI == 0) {
                    Cf[(long)z * 64 * N + (long)row * N + col] = v;
                } else if (EPI == 1) {
                    Cb[(long)row * N + col] = (bf16)(v + bias[col]);
                } else {
                    bool msk = t < declen_i[row];
                    Cf[OUT_PREDS + ((long)row * T_ + t) * V_ + col] = msk ? (v + bias[col]) : 0.f;
                }
            }
        }
    }
}

// ---------------- LN stats helper (blockDim=512) ----------------
static __device__ __forceinline__ void ln_stats(float x, float* r1, float* r2,
                                                float& m, float& var)
{
    int tid = threadIdx.x;
    r1[tid] = x; r2[tid] = x * x;
    __syncthreads();
    for (int s = 256; s > 0; s >>= 1) {
        if (tid < s) { r1[tid] += r1[tid + s]; r2[tid] += r2[tid + s]; }
        __syncthreads();
    }
    m = r1[0] * (1.f / 512.f);
    var = r2[0] * (1.f / 512.f) - m * m;
    __syncthreads();
}

// ---------------- init h,c = LN(mean_enc @ W^T + b) ----------------
__global__ __launch_bounds__(512)
void k_initln(const float* __restrict__ pi,
              const float* __restrict__ b_h, const float* __restrict__ b_c,
              const float* __restrict__ g_h, const float* __restrict__ be_h,
              const float* __restrict__ g_c, const float* __restrict__ be_c,
              bf16* __restrict__ xh, float* __restrict__ c)
{
    int b = blockIdx.x, d = threadIdx.x;
    float yh = pi[(long)b * 1024 + d]       + b_h[d];
    float yc = pi[(long)b * 1024 + 512 + d] + b_c[d];
    __shared__ float r1[512], r2[512];
    float m, v;
    ln_stats(yh, r1, r2, m, v);
    xh[(long)b * 3072 + 2560 + d] = (bf16)((yh - m) * rsqrtf(v + 1e-5f) * g_h[d] + be_h[d]);
    ln_stats(yc, r1, r2, m, v);
    c[(long)b * 512 + d] = (yc - m) * rsqrtf(v + 1e-5f) * g_c[d] + be_c[d];
}

// ---------------- alpha: e = relu(att1+att2)@Wfull, softmax, emb write -------
__global__ __launch_bounds__(256)
void k_alpha(const float* __restrict__ att2gate, const float* __restrict__ b_dec,
             const float* __restrict__ Wfull, const bf16* __restrict__ att1_b,
             const int* __restrict__ caps_i, const int* __restrict__ declen_i,
             const float* __restrict__ emb, float* __restrict__ alpha_buf,
             bf16* __restrict__ xh, float* __restrict__ out, int t)
{
    int b = blockIdx.x, tid = threadIdx.x;
    __shared__ float att2s[512], wf[512], red[256];
    for (int i = tid; i < 512; i += 256) {
        att2s[i] = att2gate[(long)b * 2560 + i] + b_dec[i];
        wf[i] = Wfull[i];
    }
    __syncthreads();
    float ev = -FLT_MAX;
    if (tid < P_) {
        const bf16* ar = att1_b + ((long)b * P_ + tid) * 512;
        float acc = 0.f;
        for (int a0 = 0; a0 < 512; a0 += 8) {
            bf16x8 v = *(const bf16x8*)(ar + a0);
#pragma unroll
            for (int j = 0; j < 8; ++j)
                acc += fmaxf((float)v[j] + att2s[a0 + j], 0.f) * wf[a0 + j];
        }
        ev = acc;   // + b_full: constant, softmax-invariant
    }
    red[tid] = ev;
    __syncthreads();
    for (int s = 128; s > 0; s >>= 1) { if (tid < s) red[tid] = fmaxf(red[tid], red[tid + s]); __syncthreads(); }
    float mx = red[0];
    __syncthreads();
    float ex = (tid < P_) ? __expf(ev - mx) : 0.f;
    red[tid] = ex;
    __syncthreads();
    for (int s = 128; s > 0; s >>= 1) { if (tid < s) red[tid] += red[tid + s]; __syncthreads(); }
    float inv = 1.f / red[0];
    if (tid < P_) {
        float al = ex * inv;
        alpha_buf[b * P_ + tid] = al;
        bool msk = t < declen_i[b];
        out[OUT_ALPH + ((long)b * T_ + t) * P_ + tid] = msk ? al : 0.f;
    }
    int tok = caps_i[b * L_ + t];
    for (int i = tid; i < 512; i += 256)
        xh[(long)b * 3072 + i] = (bf16)emb[(long)tok * 512 + i];
}

// ---------------- awe = alpha^T*enc, gated, -> xh[:,512:2560] ----------------
__global__ __launch_bounds__(256)
void k_awe(const float* __restrict__ alpha_buf, const float* __restrict__ att2gate,
           const float* __restrict__ b_beta, const bf16* __restrict__ enc_s,
           bf16* __restrict__ xh)
{
    int b = blockIdx.x, tid = threadIdx.x;
    __shared__ float alp[P_];
    if (tid < P_) alp[tid] = alpha_buf[b * P_ + tid];
    __syncthreads();
    int col = blockIdx.y * 1024 + tid * 4;
    float a0 = 0.f, a1 = 0.f, a2 = 0.f, a3 = 0.f;
    const bf16* eb = enc_s + (long)b * P_ * ENC_ + col;
    for (int p = 0; p < P_; ++p) {
        float al = alp[p];
        bf16x4 v = *(const bf16x4*)(eb + (long)p * ENC_);
        a0 += al * (float)v[0]; a1 += al * (float)v[1];
        a2 += al * (float)v[2]; a3 += al * (float)v[3];
    }
    float av[4] = {a0, a1, a2, a3};
#pragma unroll
    for (int j = 0; j < 4; ++j) {
        float g = sigmoidf_(att2gate[(long)b * 2560 + 512 + col + j] + b_beta[col + j]);
        xh[(long)b * 3072 + 512 + col + j] = (bf16)(av[j] * g);
    }
}

// ---------------- LSTM cell + 2x LayerNorm + masked state update ----------------
__global__ __launch_bounds__(512)
void k_lstm(const float* __restrict__ gp, const float* __restrict__ b_ih, const float* __restrict__ b_hh,
            const float* __restrict__ g_h, const float* __restrict__ be_h,
            const float* __restrict__ g_c, const float* __restrict__ be_c,
            bf16* __restrict__ xh, float* __restrict__ c,
            const int* __restrict__ declen_i, int t)
{
    int b = blockIdx.x, d = threadIdx.x;
    float iv = b_ih[d]        + b_hh[d];
    float fv = b_ih[512 + d]  + b_hh[512 + d];
    float gv = b_ih[1024 + d] + b_hh[1024 + d];
    float ov = b_ih[1536 + d] + b_hh[1536 + d];
    for (int s = 0; s < 4; ++s) {
        const float* gs = gp + ((long)s * B_ + b) * 2048;
        iv += gs[d]; fv += gs[512 + d]; gv += gs[1024 + d]; ov += gs[1536 + d];
    }
    float cn = sigmoidf_(fv) * c[(long)b * 512 + d] + sigmoidf_(iv) * tanhf(gv);
    float hn = sigmoidf_(ov) * tanhf(cn);
    __shared__ float r1[512], r2[512];
    float m, v;
    ln_stats(hn, r1, r2, m, v);
    float hln = (hn - m) * rsqrtf(v + 1e-5f) * g_h[d] + be_h[d];
    ln_stats(cn, r1, r2, m, v);
    float cln = (cn - m) * rsqrtf(v + 1e-5f) * g_c[d] + be_c[d];
    if (t < declen_i[b]) {
        xh[(long)b * 3072 + 2560 + d] = (bf16)hln;
        c[(long)b * 512 + d] = cln;
    }
}

extern "C" void kernel_launch(void* const* d_in, const int* in_sizes, int n_in,
                              void* d_out, int out_size, void* d_ws, size_t ws_size,
                              hipStream_t stream)
{
    const float* enc       = (const float*)d_in[0];
    const int*   caps      = (const int*)  d_in[1];
    const int*   caplen    = (const int*)  d_in[2];
    const float* emb       = (const float*)d_in[3];
    const float* W_enc_att = (const float*)d_in[4];
    const float* b_enc_att = (const float*)d_in[5];
    const float* W_dec_att = (const float*)d_in[6];
    const float* b_dec_att = (const float*)d_in[7];
    const float* W_full    = (const float*)d_in[8];
    // d_in[9] = b_full (softmax-invariant, unused)
    const float* W_ih      = (const float*)d_in[10];
    const float* b_ih      = (const float*)d_in[11];
    const float* W_hh      = (const float*)d_in[12];
    const float* b_hh      = (const float*)d_in[13];
    const float* g_h       = (const float*)d_in[14];
    const float* be_h      = (const float*)d_in[15];
    const float* g_c       = (const float*)d_in[16];
    const float* be_c      = (const float*)d_in[17];
    const float* W_init_h  = (const float*)d_in[18];
    const float* b_init_h  = (const float*)d_in[19];
    const float* W_init_c  = (const float*)d_in[20];
    const float* b_init_c  = (const float*)d_in[21];
    const float* W_beta    = (const float*)d_in[22];
    const float* b_beta    = (const float*)d_in[23];
    const float* W_fc      = (const float*)d_in[24];
    const float* b_fc      = (const float*)d_in[25];
    float* out = (float*)d_out;

    char* w = (char*)d_ws;
    auto alloc = [&](size_t bytes) { char* p = w; w += (bytes + 255) & ~(size_t)255; return p; };
    int*   order_i  = (int*)  alloc(B_ * 4);
    int*   declen_i = (int*)  alloc(B_ * 4);
    int*   caps_i   = (int*)  alloc(B_ * L_ * 4);
    bf16*  enc_s    = (bf16*) alloc((size_t)B_ * P_ * ENC_ * 2);
    bf16*  mean_b   = (bf16*) alloc((size_t)B_ * ENC_ * 2);
    bf16*  att1_b   = (bf16*) alloc((size_t)B_ * P_ * 512 * 2);
    float* pi       = (float*)alloc((size_t)B_ * 1024 * 4);
    float* att2gate = (float*)alloc((size_t)B_ * 2560 * 4);
    float* alpha_b  = (float*)alloc((size_t)B_ * P_ * 4);
    bf16*  xh       = (bf16*) alloc((size_t)B_ * 3072 * 2);
    float* gp       = (float*)alloc((size_t)4 * B_ * 2048 * 4);
    float* cbuf     = (float*)alloc((size_t)B_ * 512 * 4);
    bf16*  W_enc_b  = (bf16*) alloc((size_t)512 * 2048 * 2);
    bf16*  W_dec_b  = (bf16*) alloc((size_t)512 * 512 * 2);
    bf16*  W_beta_b = (bf16*) alloc((size_t)2048 * 512 * 2);
    bf16*  W_ih_b   = (bf16*) alloc((size_t)2048 * 2560 * 2);
    bf16*  W_hh_b   = (bf16*) alloc((size_t)2048 * 512 * 2);
    bf16*  W_fc_b   = (bf16*) alloc((size_t)32000 * 512 * 2);
    bf16*  W_inh_b  = (bf16*) alloc((size_t)512 * 2048 * 2);
    bf16*  W_inc_b  = (bf16*) alloc((size_t)512 * 2048 * 2);

    k_order<<<1, B_, 0, stream>>>(caplen, caps, order_i, declen_i, caps_i, out);
    k_cvt_enc<<<12544, 256, 0, stream>>>(enc, order_i, enc_s);
    k_meanb<<<dim3(B_, 8), 256, 0, stream>>>(enc_s, mean_b);

    auto cvt = [&](const float* src, bf16* dst, long n) {
        k_cvt<<<(int)((n / 8 + 255) / 256), 256, 0, stream>>>(src, dst, n);
    };
    cvt(W_enc_att, W_enc_b, 512L * 2048);
    cvt(W_dec_att, W_dec_b, 512L * 512);
    cvt(W_beta,    W_beta_b, 2048L * 512);
    cvt(W_ih,      W_ih_b,  2048L * 2560);
    cvt(W_hh,      W_hh_b,  2048L * 512);
    cvt(W_fc,      W_fc_b,  32000L * 512);
    cvt(W_init_h,  W_inh_b, 512L * 2048);
    cvt(W_init_c,  W_inc_b, 512L * 2048);

    // init: [h|c] = mean_b @ [W_init_h|W_init_c]^T  (N-split), then LN
    k_mgemm<1, 0><<<dim3(1, 8, 1), 256, 0, stream>>>(mean_b, 2048, W_inh_b, W_inc_b,
        nullptr, pi, nullptr, 1024, 2048, 1, 512, 0, 0, nullptr);
    k_initln<<<B_, 512, 0, stream>>>(pi, b_init_h, b_init_c, g_h, be_h, g_c, be_c, xh, cbuf);

    // att1 = enc_s @ W_enc^T + b  -> bf16 [12544][512]
    k_mgemm<0, 1><<<dim3(196, 4, 1), 256, 0, stream>>>(enc_s, 2048, W_enc_b, nullptr,
        b_enc_att, nullptr, att1_b, 512, 2048, 1, 0, 0, 0, nullptr);

    for (int t = 0; t < T_; ++t) {
        // [att2|gate_pre] = h @ [W_dec|W_beta]^T  (N-split, raw)
        k_mgemm<1, 0><<<dim3(1, 20, 1), 256, 0, stream>>>(xh + 2560, 3072, W_dec_b, W_beta_b,
            nullptr, att2gate, nullptr, 2560, 512, 1, 512, 0, 0, nullptr);
        k_alpha<<<B_, 256, 0, stream>>>(att2gate, b_dec_att, W_full, att1_b,
            caps_i, declen_i, emb, alpha_b, xh, out, t);
        k_awe<<<dim3(B_, 2), 256, 0, stream>>>(alpha_b, att2gate, b_beta, enc_s, xh);
        // gates = xh @ [W_ih ; W_hh]^T (K-split at 2560, split-K S=4)
        k_mgemm<2, 0><<<dim3(1, 16, 4), 256, 0, stream>>>(xh, 3072, W_ih_b, W_hh_b,
            nullptr, gp, nullptr, 2048, 3072, 4, 0, 2560, 0, nullptr);
        k_lstm<<<B_, 512, 0, stream>>>(gp, b_ih, b_hh, g_h, be_h, g_c, be_c, xh, cbuf, declen_i, t);
        // preds = h @ W_fc^T + b_fc (masked write into out)
        k_mgemm<0, 2><<<dim3(1, 250, 1), 256, 0, stream>>>(xh + 2560, 3072, W_fc_b, nullptr,
            b_fc, out, nullptr, V_, 512, 1, 0, 0, t, declen_i);
    }
}

// Round 3
// 2493.115 us; speedup vs baseline: 2.8692x; 1.2114x over previous
//
#include <hip/hip_runtime.h>
#include <cfloat>
#include <math.h>

#define B_ 64
#define P_ 196
#define ENC_ 2048
#define D_ 512
#define V_ 32000
#define L_ 32
#define T_ 31

// flat f32 output layout (reference return order)
#define OUT_PREDS 0L
#define OUT_CAPS  63488000L              // 64*31*32000
#define OUT_DECL  63490048L              // +64*32
#define OUT_ALPH  63490112L              // +64
#define OUT_ORDER 63878976L              // +64*31*196

typedef __bf16 bf16;
typedef __bf16 bf16x8 __attribute__((ext_vector_type(8)));
typedef __bf16 bf16x4 __attribute__((ext_vector_type(4)));
typedef float  f32x4  __attribute__((ext_vector_type(4)));

static __device__ __forceinline__ float sigmoidf_(float x) { return 1.f / (1.f + __expf(-x)); }

// ---------------- sort by length, caps gather, scalar outputs ----------------
__global__ void k_order(const int* __restrict__ cap_len, const int* __restrict__ caps,
                        int* __restrict__ order_i, int* __restrict__ declen_i,
                        int* __restrict__ caps_i, float* __restrict__ out)
{
    __shared__ int len_s[B_];
    int tid = threadIdx.x;
    len_s[tid] = cap_len[tid];
    __syncthreads();
    int li = len_s[tid];
    int pos = 0;
    for (int j = 0; j < B_; ++j) {
        int lj = len_s[j];
        pos += (lj > li) || (lj == li && j < tid);   // stable descending rank
    }
    order_i[pos]  = tid;
    declen_i[pos] = li - 1;
    out[OUT_ORDER + pos] = (float)tid;
    out[OUT_DECL  + pos] = (float)(li - 1);
    for (int l = 0; l < L_; ++l) {
        int tok = caps[tid * L_ + l];
        caps_i[pos * L_ + l] = tok;
        out[OUT_CAPS + pos * L_ + l] = (float)tok;
    }
}

// ---------------- f32 -> bf16 convert (8/thread) ----------------
__global__ __launch_bounds__(256) void k_cvt(const float* __restrict__ in, bf16* __restrict__ ob, long n)
{
    long i = ((long)blockIdx.x * 256 + threadIdx.x) * 8;
    if (i >= n) return;
    float4 a = *(const float4*)(in + i);
    float4 b = *(const float4*)(in + i + 4);
    bf16x8 v;
    v[0]=(bf16)a.x; v[1]=(bf16)a.y; v[2]=(bf16)a.z; v[3]=(bf16)a.w;
    v[4]=(bf16)b.x; v[5]=(bf16)b.y; v[6]=(bf16)b.z; v[7]=(bf16)b.w;
    *(bf16x8*)(ob + i) = v;
}

// ---------------- enc gather-by-order + convert to bf16 ----------------
__global__ __launch_bounds__(256) void k_cvt_enc(const float* __restrict__ enc,
                                                 const int* __restrict__ order_i,
                                                 bf16* __restrict__ enc_s)
{
    long i = ((long)blockIdx.x * 256 + threadIdx.x) * 8;
    int b = (int)(i / ((long)P_ * ENC_));
    long rem = i - (long)b * P_ * ENC_;
    const float* src = enc + (long)order_i[b] * P_ * ENC_ + rem;
    float4 a = *(const float4*)(src);
    float4 c = *(const float4*)(src + 4);
    bf16x8 v;
    v[0]=(bf16)a.x; v[1]=(bf16)a.y; v[2]=(bf16)a.z; v[3]=(bf16)a.w;
    v[4]=(bf16)c.x; v[5]=(bf16)c.y; v[6]=(bf16)c.z; v[7]=(bf16)c.w;
    *(bf16x8*)(enc_s + i) = v;
}

// ---------------- mean over pixels (bf16 in/out) ----------------
__global__ __launch_bounds__(256) void k_meanb(const bf16* __restrict__ enc_s, bf16* __restrict__ mean_b)
{
    int b = blockIdx.x, col = blockIdx.y * 256 + threadIdx.x;
    float s = 0.f;
    const bf16* eb = enc_s + (long)b * P_ * ENC_ + col;
    for (int p = 0; p < P_; ++p) s += (float)eb[(long)p * ENC_];
    mean_b[(long)b * ENC_ + col] = (bf16)(s * (1.f / (float)P_));
}

// ---------------- MFMA GEMM: C[M][N] = A[M][K](bf16) * B[N][K]^T(bf16) ------
// 256 thr = 4 waves; tile BM=64 x BN=128; wave w covers cols [w*32, w*32+32).
// Software-pipelined fragment prefetch; no LDS.
// FUSE: 0=single B, 1=N-split (B2 rows from n>=Nsp), 2=K-split (B2 cols from k>=Ksp)
// EPI:  0=RAW f32 partial slot z (M=64), 1=bf16 +bias (att1), 2=masked preds +bias (hseq rows)
// SWZ:  0=blockIdx 3D; 1=att1 1D 784 blocks XCD-chunked; 2=preds 1D 7750 blocks XCD-chunked
template<int FUSE, int EPI, int SWZ>
__global__ void __launch_bounds__(256)
k_mgemm(const bf16* __restrict__ A, long lda,
        const bf16* __restrict__ B1, const bf16* __restrict__ B2,
        const float* __restrict__ bias,
        float* __restrict__ Cf, bf16* __restrict__ Cb,
        int N, int K, int kspl, int Nsp, int Ksp,
        const int* __restrict__ declen_i)
{
    const int tid = threadIdx.x;
    const int lane = tid & 63, w = tid >> 6;
    int mt, nt, z;
    if (SWZ == 0)      { mt = blockIdx.x; nt = blockIdx.y; z = blockIdx.z; }
    else if (SWZ == 1) { int o = blockIdx.x; int wg = (o & 7) * 98 + (o >> 3);
                         mt = wg >> 2; nt = wg & 3; z = 0; }
    else               { int o = blockIdx.x; int xcd = o & 7;
                         int base = xcd < 6 ? xcd * 969 : 5814 + (xcd - 6) * 968;
                         int wg = base + (o >> 3);
                         nt = wg / 31; mt = wg - 31 * nt; z = 0; }
    const int krange = K / kspl;
    const int k0 = z * krange, k1 = k0 + krange;
    const int r16 = lane & 15, kq = lane >> 4;
    const int koff = kq * 8;

    const bf16* Ap = A + (long)(mt * 64 + r16) * lda + koff;
    const int ncol0 = nt * 128 + w * 32;

    const bf16* Bp[2];
    const bf16* B2p[2];
#pragma unroll
    for (int ni = 0; ni < 2; ++ni) {
        int n = ncol0 + ni * 16 + r16;
        if (FUSE == 1)
            Bp[ni] = (n < Nsp) ? B1 + (long)n * K + koff
                               : B2 + (long)(n - Nsp) * K + koff;
        else if (FUSE == 2) {
            Bp[ni]  = B1 + (long)n * Ksp + koff;
            B2p[ni] = B2 + (long)n * (K - Ksp) + koff - Ksp;  // +kk yields col kk-Ksp
        } else
            Bp[ni] = B1 + (long)n * K + koff;
    }

    auto loadA = [&](int kk, bf16x8* dst) {
#pragma unroll
        for (int mi = 0; mi < 4; ++mi)
            dst[mi] = *(const bf16x8*)(Ap + (long)mi * 16 * lda + kk);
    };
    auto loadB = [&](int kk, bf16x8* dst) {
#pragma unroll
        for (int ni = 0; ni < 2; ++ni) {
            if (FUSE == 2 && kk >= Ksp) dst[ni] = *(const bf16x8*)(B2p[ni] + kk);
            else                        dst[ni] = *(const bf16x8*)(Bp[ni] + kk);
        }
    };

    f32x4 acc[4][2] = {};
    bf16x8 af[4], bfr[2];
    loadA(k0, af); loadB(k0, bfr);
    for (int kk = k0 + 32; kk < k1; kk += 32) {
        bf16x8 af2[4], bf2[2];
        loadA(kk, af2); loadB(kk, bf2);
#pragma unroll
        for (int mi = 0; mi < 4; ++mi)
#pragma unroll
            for (int ni = 0; ni < 2; ++ni)
                acc[mi][ni] = __builtin_amdgcn_mfma_f32_16x16x32_bf16(af[mi], bfr[ni], acc[mi][ni], 0, 0, 0);
#pragma unroll
        for (int mi = 0; mi < 4; ++mi) af[mi] = af2[mi];
#pragma unroll
        for (int ni = 0; ni < 2; ++ni) bfr[ni] = bf2[ni];
    }
#pragma unroll
    for (int mi = 0; mi < 4; ++mi)
#pragma unroll
        for (int ni = 0; ni < 2; ++ni)
            acc[mi][ni] = __builtin_amdgcn_mfma_f32_16x16x32_bf16(af[mi], bfr[ni], acc[mi][ni], 0, 0, 0);

    // C/D layout (m89-verified): col = lane&15, row = (lane>>4)*4 + r
#pragma unroll
    for (int mi = 0; mi < 4; ++mi) {
#pragma unroll
        for (int ni = 0; ni < 2; ++ni) {
            int col = ncol0 + ni * 16 + r16;
#pragma unroll
            for (int r = 0; r < 4; ++r) {
                int row = mt * 64 + mi * 16 + kq * 4 + r;
                float v = acc[mi][ni][r];
                if (EPI == 0) {
                    Cf[(long)z * 64 * N + (long)row * N + col] = v;
                } else if (EPI == 1) {
                    Cb[(long)row * N + col] = (bf16)(v + bias[col]);
                } else { // row encodes t*64+b over hseq
                    int tt = row >> 6, b = row & 63;
                    bool msk = tt < declen_i[b];
                    Cf[OUT_PREDS + ((long)b * T_ + tt) * V_ + col] = msk ? (v + bias[col]) : 0.f;
                }
            }
        }
    }
}

// ---------------- LN stats helper (blockDim=512) ----------------
static __device__ __forceinline__ void ln_stats(float x, float* r1, float* r2,
                                                float& m, float& var)
{
    int tid = threadIdx.x;
    r1[tid] = x; r2[tid] = x * x;
    __syncthreads();
    for (int s = 256; s > 0; s >>= 1) {
        if (tid < s) { r1[tid] += r1[tid + s]; r2[tid] += r2[tid + s]; }
        __syncthreads();
    }
    m = r1[0] * (1.f / 512.f);
    var = r2[0] * (1.f / 512.f) - m * m;
    __syncthreads();
}

// ---------------- init h,c = LN(mean_enc @ W^T + b) ----------------
__global__ __launch_bounds__(512)
void k_initln(const float* __restrict__ pi,
              const float* __restrict__ b_h, const float* __restrict__ b_c,
              const float* __restrict__ g_h, const float* __restrict__ be_h,
              const float* __restrict__ g_c, const float* __restrict__ be_c,
              bf16* __restrict__ xh, float* __restrict__ c)
{
    int b = blockIdx.x, d = threadIdx.x;
    float yh = pi[(long)b * 1024 + d]       + b_h[d];
    float yc = pi[(long)b * 1024 + 512 + d] + b_c[d];
    __shared__ float r1[512], r2[512];
    float m, v;
    ln_stats(yh, r1, r2, m, v);
    xh[(long)b * 3072 + 2560 + d] = (bf16)((yh - m) * rsqrtf(v + 1e-5f) * g_h[d] + be_h[d]);
    ln_stats(yc, r1, r2, m, v);
    c[(long)b * 512 + d] = (yc - m) * rsqrtf(v + 1e-5f) * g_c[d] + be_c[d];
}

// ------- fused attention: e/softmax/alpha-out + awe*gate + emb, one block/b --------
// att2gate: 4 raw split-K slots of [64][2560] f32; [0:512]=att2pre, [512:2560]=gate_pre
__global__ __launch_bounds__(512)
void k_attn(const float* __restrict__ att2gate, const float* __restrict__ b_dec,
            const float* __restrict__ b_beta, const float* __restrict__ Wfull,
            const bf16* __restrict__ att1_b, const bf16* __restrict__ enc_s,
            const int* __restrict__ caps_i, const int* __restrict__ declen_i,
            const float* __restrict__ emb,
            bf16* __restrict__ xh, float* __restrict__ out, int t)
{
    const int b = blockIdx.x, tid = threadIdx.x;
    __shared__ float att2s[512], wf[512], red[512];
    __shared__ float alp[P_];
    {
        float s = b_dec[tid];
#pragma unroll
        for (int zz = 0; zz < 4; ++zz) s += att2gate[((long)zz * 64 + b) * 2560 + tid];
        att2s[tid] = s;
        wf[tid] = Wfull[tid];
    }
    __syncthreads();
    float ev = -FLT_MAX;
    if (tid < P_) {
        const bf16* ar = att1_b + ((long)b * P_ + tid) * 512;
        float acc = 0.f;
        for (int a0 = 0; a0 < 512; a0 += 8) {
            bf16x8 v = *(const bf16x8*)(ar + a0);
#pragma unroll
            for (int j = 0; j < 8; ++j)
                acc += fmaxf((float)v[j] + att2s[a0 + j], 0.f) * wf[a0 + j];
        }
        ev = acc;   // + b_full: softmax-invariant
    }
    red[tid] = ev;
    __syncthreads();
    for (int s = 256; s > 0; s >>= 1) { if (tid < s) red[tid] = fmaxf(red[tid], red[tid + s]); __syncthreads(); }
    float mx = red[0];
    __syncthreads();
    float ex = (tid < P_) ? __expf(ev - mx) : 0.f;
    red[tid] = ex;
    __syncthreads();
    for (int s = 256; s > 0; s >>= 1) { if (tid < s) red[tid] += red[tid + s]; __syncthreads(); }
    float inv = 1.f / red[0];
    bool msk = t < declen_i[b];
    if (tid < P_) {
        float al = ex * inv;
        alp[tid] = al;
        out[OUT_ALPH + ((long)b * T_ + t) * P_ + tid] = msk ? al : 0.f;
    }
    __syncthreads();
    // awe: 4 cols per thread
    const int col = tid * 4;
    float a0 = 0.f, a1 = 0.f, a2 = 0.f, a3 = 0.f;
    const bf16* eb = enc_s + (long)b * P_ * ENC_ + col;
#pragma unroll 4
    for (int p = 0; p < P_; ++p) {
        bf16x4 v = *(const bf16x4*)(eb + (long)p * ENC_);
        float al = alp[p];
        a0 += al * (float)v[0]; a1 += al * (float)v[1];
        a2 += al * (float)v[2]; a3 += al * (float)v[3];
    }
    float av[4] = {a0, a1, a2, a3};
#pragma unroll
    for (int j = 0; j < 4; ++j) {
        float gpre = b_beta[col + j];
#pragma unroll
        for (int zz = 0; zz < 4; ++zz) gpre += att2gate[((long)zz * 64 + b) * 2560 + 512 + col + j];
        xh[(long)b * 3072 + 512 + col + j] = (bf16)(av[j] * sigmoidf_(gpre));
    }
    // x[:, 0:512] = embedding of token t
    int tok = caps_i[b * L_ + t];
    xh[(long)b * 3072 + tid] = (bf16)emb[(long)tok * 512 + tid];
}

// ---------------- LSTM cell + 2x LayerNorm + masked update + hseq record ----------------
__global__ __launch_bounds__(512)
void k_lstm(const float* __restrict__ gp, const float* __restrict__ b_ih, const float* __restrict__ b_hh,
            const float* __restrict__ g_h, const float* __restrict__ be_h,
            const float* __restrict__ g_c, const float* __restrict__ be_c,
            bf16* __restrict__ xh, float* __restrict__ c, bf16* __restrict__ hseq,
            const int* __restrict__ declen_i, int t)
{
    int b = blockIdx.x, d = threadIdx.x;
    float iv = b_ih[d]        + b_hh[d];
    float fv = b_ih[512 + d]  + b_hh[512 + d];
    float gv = b_ih[1024 + d] + b_hh[1024 + d];
    float ov = b_ih[1536 + d] + b_hh[1536 + d];
    for (int s = 0; s < 8; ++s) {
        const float* gs = gp + ((long)s * B_ + b) * 2048;
        iv += gs[d]; fv += gs[512 + d]; gv += gs[1024 + d]; ov += gs[1536 + d];
    }
    float cn = sigmoidf_(fv) * c[(long)b * 512 + d] + sigmoidf_(iv) * tanhf(gv);
    float hn = sigmoidf_(ov) * tanhf(cn);
    __shared__ float r1[512], r2[512];
    float m, v;
    ln_stats(hn, r1, r2, m, v);
    float hln = (hn - m) * rsqrtf(v + 1e-5f) * g_h[d] + be_h[d];
    ln_stats(cn, r1, r2, m, v);
    float cln = (cn - m) * rsqrtf(v + 1e-5f) * g_c[d] + be_c[d];
    bool msk = t < declen_i[b];
    bf16 hold = xh[(long)b * 3072 + 2560 + d];
    bf16 hv = msk ? (bf16)hln : hold;
    xh[(long)b * 3072 + 2560 + d] = hv;
    hseq[((long)t * B_ + b) * 512 + d] = hv;
    if (msk) c[(long)b * 512 + d] = cln;
}

extern "C" void kernel_launch(void* const* d_in, const int* in_sizes, int n_in,
                              void* d_out, int out_size, void* d_ws, size_t ws_size,
                              hipStream_t stream)
{
    const float* enc       = (const float*)d_in[0];
    const int*   caps      = (const int*)  d_in[1];
    const int*   caplen    = (const int*)  d_in[2];
    const float* emb       = (const float*)d_in[3];
    const float* W_enc_att = (const float*)d_in[4];
    const float* b_enc_att = (const float*)d_in[5];
    const float* W_dec_att = (const float*)d_in[6];
    const float* b_dec_att = (const float*)d_in[7];
    const float* W_full    = (const float*)d_in[8];
    // d_in[9] = b_full (softmax-invariant, unused)
    const float* W_ih      = (const float*)d_in[10];
    const float* b_ih      = (const float*)d_in[11];
    const float* W_hh      = (const float*)d_in[12];
    const float* b_hh      = (const float*)d_in[13];
    const float* g_h       = (const float*)d_in[14];
    const float* be_h      = (const float*)d_in[15];
    const float* g_c       = (const float*)d_in[16];
    const float* be_c      = (const float*)d_in[17];
    const float* W_init_h  = (const float*)d_in[18];
    const float* b_init_h  = (const float*)d_in[19];
    const float* W_init_c  = (const float*)d_in[20];
    const float* b_init_c  = (const float*)d_in[21];
    const float* W_beta    = (const float*)d_in[22];
    const float* b_beta    = (const float*)d_in[23];
    const float* W_fc      = (const float*)d_in[24];
    const float* b_fc      = (const float*)d_in[25];
    float* out = (float*)d_out;

    char* w = (char*)d_ws;
    auto alloc = [&](size_t bytes) { char* p = w; w += (bytes + 255) & ~(size_t)255; return p; };
    int*   order_i  = (int*)  alloc(B_ * 4);
    int*   declen_i = (int*)  alloc(B_ * 4);
    int*   caps_i   = (int*)  alloc(B_ * L_ * 4);
    bf16*  enc_s    = (bf16*) alloc((size_t)B_ * P_ * ENC_ * 2);
    bf16*  mean_b   = (bf16*) alloc((size_t)B_ * ENC_ * 2);
    bf16*  att1_b   = (bf16*) alloc((size_t)B_ * P_ * 512 * 2);
    float* pi       = (float*)alloc((size_t)B_ * 1024 * 4);
    float* att2gate = (float*)alloc((size_t)4 * B_ * 2560 * 4);
    bf16*  xh       = (bf16*) alloc((size_t)B_ * 3072 * 2);
    float* gp       = (float*)alloc((size_t)8 * B_ * 2048 * 4);
    float* cbuf     = (float*)alloc((size_t)B_ * 512 * 4);
    bf16*  hseq     = (bf16*) alloc((size_t)T_ * B_ * 512 * 2);
    bf16*  W_enc_b  = (bf16*) alloc((size_t)512 * 2048 * 2);
    bf16*  W_dec_b  = (bf16*) alloc((size_t)512 * 512 * 2);
    bf16*  W_beta_b = (bf16*) alloc((size_t)2048 * 512 * 2);
    bf16*  W_ih_b   = (bf16*) alloc((size_t)2048 * 2560 * 2);
    bf16*  W_hh_b   = (bf16*) alloc((size_t)2048 * 512 * 2);
    bf16*  W_fc_b   = (bf16*) alloc((size_t)32000 * 512 * 2);
    bf16*  W_inh_b  = (bf16*) alloc((size_t)512 * 2048 * 2);
    bf16*  W_inc_b  = (bf16*) alloc((size_t)512 * 2048 * 2);

    k_order<<<1, B_, 0, stream>>>(caplen, caps, order_i, declen_i, caps_i, out);
    k_cvt_enc<<<12544, 256, 0, stream>>>(enc, order_i, enc_s);
    k_meanb<<<dim3(B_, 8), 256, 0, stream>>>(enc_s, mean_b);

    auto cvt = [&](const float* src, bf16* dst, long n) {
        k_cvt<<<(int)((n / 8 + 255) / 256), 256, 0, stream>>>(src, dst, n);
    };
    cvt(W_enc_att, W_enc_b, 512L * 2048);
    cvt(W_dec_att, W_dec_b, 512L * 512);
    cvt(W_beta,    W_beta_b, 2048L * 512);
    cvt(W_ih,      W_ih_b,  2048L * 2560);
    cvt(W_hh,      W_hh_b,  2048L * 512);
    cvt(W_fc,      W_fc_b,  32000L * 512);
    cvt(W_init_h,  W_inh_b, 512L * 2048);
    cvt(W_init_c,  W_inc_b, 512L * 2048);

    // init: [h|c] = mean_b @ [W_init_h|W_init_c]^T  (N-split), then LN
    k_mgemm<1, 0, 0><<<dim3(1, 8, 1), 256, 0, stream>>>(mean_b, 2048, W_inh_b, W_inc_b,
        nullptr, pi, nullptr, 1024, 2048, 1, 512, 0, nullptr);
    k_initln<<<B_, 512, 0, stream>>>(pi, b_init_h, b_init_c, g_h, be_h, g_c, be_c, xh, cbuf);

    // att1 = enc_s @ W_enc^T + b -> bf16 [12544][512]; 784 blocks XCD-chunked
    k_mgemm<0, 1, 1><<<784, 256, 0, stream>>>(enc_s, 2048, W_enc_b, nullptr,
        b_enc_att, nullptr, att1_b, 512, 2048, 1, 0, 0, nullptr);

    for (int t = 0; t < T_; ++t) {
        // [att2|gate_pre] = h @ [W_dec|W_beta]^T  (N-split, split-K S=4 raw slots)
        k_mgemm<1, 0, 0><<<dim3(1, 20, 4), 256, 0, stream>>>(xh + 2560, 3072, W_dec_b, W_beta_b,
            nullptr, att2gate, nullptr, 2560, 512, 4, 512, 0, nullptr);
        k_attn<<<B_, 512, 0, stream>>>(att2gate, b_dec_att, b_beta, W_full, att1_b, enc_s,
            caps_i, declen_i, emb, xh, out, t);
        // gates = xh @ [W_ih ; W_hh]^T (K-split at 2560, split-K S=8)
        k_mgemm<2, 0, 0><<<dim3(1, 16, 8), 256, 0, stream>>>(xh, 3072, W_ih_b, W_hh_b,
            nullptr, gp, nullptr, 2048, 3072, 8, 0, 2560, nullptr);
        k_lstm<<<B_, 512, 0, stream>>>(gp, b_ih, b_hh, g_h, be_h, g_c, be_c,
            xh, cbuf, hseq, declen_i, t);
    }

    // preds = hseq @ W_fc^T + b_fc (M=1984, masked scatter); 7750 blocks XCD-chunked
    k_mgemm<0, 2, 2><<<7750, 256, 0, stream>>>(hseq, 512, W_fc_b, nullptr,
        b_fc, out, nullptr, V_, 512, 1, 0, 0, declen_i);
}